// Round 1
// baseline (3133.372 us; speedup 1.0000x reference)
//
#include <hip/hip_runtime.h>

#define NN 100000
#define NE 1600000

// ---------------- preprocessing ----------------

__global__ void count_kernel(const int* __restrict__ dst, int* __restrict__ cnt) {
    int e = blockIdx.x * blockDim.x + threadIdx.x;
    if (e < NE) atomicAdd(&cnt[dst[e]], 1);
}

__global__ void dis_kernel(const int* __restrict__ cnt, float* __restrict__ dis) {
    int i = blockIdx.x * blockDim.x + threadIdx.x;
    if (i < NN) dis[i] = rsqrtf((float)(cnt[i] + 1));  // +1 self loop, deg >= 1 always
}

__global__ __launch_bounds__(1024) void scan_kernel(const int* __restrict__ cnt,
                                                    int* __restrict__ row_ptr) {
    __shared__ int sdata[1024];
    __shared__ int sbase;
    int t = threadIdx.x;
    if (t == 0) sbase = 0;
    __syncthreads();
    for (int base = 0; base < NN; base += 4096) {
        int idx = base + t * 4;
        int v0 = (idx + 0 < NN) ? cnt[idx + 0] : 0;
        int v1 = (idx + 1 < NN) ? cnt[idx + 1] : 0;
        int v2 = (idx + 2 < NN) ? cnt[idx + 2] : 0;
        int v3 = (idx + 3 < NN) ? cnt[idx + 3] : 0;
        int s = v0 + v1 + v2 + v3;
        sdata[t] = s;
        __syncthreads();
        for (int off = 1; off < 1024; off <<= 1) {
            int xv = (t >= off) ? sdata[t - off] : 0;
            __syncthreads();
            sdata[t] += xv;
            __syncthreads();
        }
        int incl = sdata[t];
        int p = sbase + incl - s;
        if (idx + 0 < NN) row_ptr[idx + 0] = p;
        if (idx + 1 < NN) row_ptr[idx + 1] = p + v0;
        if (idx + 2 < NN) row_ptr[idx + 2] = p + v0 + v1;
        if (idx + 3 < NN) row_ptr[idx + 3] = p + v0 + v1 + v2;
        __syncthreads();
        if (t == 1023) sbase = sbase + incl;
        __syncthreads();
    }
    if (t == 0) row_ptr[NN] = sbase;
}

__global__ void fill_kernel(const int* __restrict__ src, const int* __restrict__ dst,
                            const int* __restrict__ row_ptr, int* __restrict__ fil,
                            const float* __restrict__ dis,
                            int* __restrict__ col, float* __restrict__ val) {
    int e = blockIdx.x * blockDim.x + threadIdx.x;
    if (e >= NE) return;
    int d = dst[e], s = src[e];
    int pos = atomicAdd(&fil[d], 1);
    int o = row_ptr[d] + pos;
    col[o] = s;
    val[o] = dis[s] * dis[d];
}

// ax = Ahat @ x   (width 3)
__global__ void aggx_kernel(const float* __restrict__ x, const int* __restrict__ row_ptr,
                            const int* __restrict__ col, const float* __restrict__ val,
                            const float* __restrict__ dis, float* __restrict__ ax) {
    int i = blockIdx.x * blockDim.x + threadIdx.x;
    if (i >= NN) return;
    float di = dis[i], w = di * di;
    float a0 = w * x[i * 3 + 0], a1 = w * x[i * 3 + 1], a2 = w * x[i * 3 + 2];
    int e = row_ptr[i + 1];
    for (int p = row_ptr[i]; p < e; ++p) {
        int j = col[p]; float v = val[p];
        a0 += v * x[j * 3 + 0];
        a1 += v * x[j * 3 + 1];
        a2 += v * x[j * 3 + 2];
    }
    ax[i * 3 + 0] = a0; ax[i * 3 + 1] = a1; ax[i * 3 + 2] = a2;
}

// t0 = relu(ax @ Wp + bp)   and   xr = ax @ Wr[64:67,:] + br   (both pure dense)
__global__ void proj_kernel(const float* __restrict__ ax,
                            const float* __restrict__ Wp, const float* __restrict__ bp,
                            const float* __restrict__ Wr, const float* __restrict__ br,
                            float* __restrict__ t0, float* __restrict__ xr) {
    int g = blockIdx.x * blockDim.x + threadIdx.x;
    if (g >= NN * 64) return;
    int i = g >> 6, c = g & 63;
    float a0 = ax[i * 3 + 0], a1 = ax[i * 3 + 1], a2 = ax[i * 3 + 2];
    float tp = a0 * Wp[c] + a1 * Wp[64 + c] + a2 * Wp[128 + c] + bp[c];
    t0[g] = fmaxf(tp, 0.f);
    xr[g] = a0 * Wr[64 * 64 + c] + a1 * Wr[65 * 64 + c] + a2 * Wr[66 * 64 + c] + br[c];
}

// ---------------- fused GCN: out = act( (Ahat h) @ W + bias + add ) ----------------

template <int IN_W, int OUT_W, bool RELU, bool HAS_ADD, bool HAS_BIAS>
__global__ __launch_bounds__(256) void gcn_kernel(
    const float* __restrict__ h, const float* __restrict__ Wg,
    const float* __restrict__ bias, const float* __restrict__ addsrc,
    const int* __restrict__ row_ptr, const int* __restrict__ colv,
    const float* __restrict__ valv, const float* __restrict__ dis,
    float* __restrict__ out) {
    constexpr int TILE_R = 64;
    constexpr int STR = TILE_R + 4;  // pad keeps float4 alignment, breaks pow2 stride
    __shared__ __align__(16) float aggT[IN_W][STR];  // feature-major staging
    __shared__ __align__(16) float Wl[IN_W][OUT_W];

    const int tid = threadIdx.x;
    for (int idx = tid; idx < IN_W * OUT_W; idx += 256) (&Wl[0][0])[idx] = Wg[idx];

    const int tile0 = blockIdx.x * TILE_R;
    const int wave = tid >> 6;
    const int lane = tid & 63;

    // phase 1: each of 4 waves aggregates 16 rows, lane = feature
    for (int rr = 0; rr < 16; ++rr) {
        const int rl = (wave << 4) + rr;
        const int i = tile0 + rl;
        float acc = 0.f;
        if (i < NN) {
            const float di = dis[i];
            if (lane < IN_W) acc = di * di * h[i * IN_W + lane];
            int s = __builtin_amdgcn_readfirstlane(row_ptr[i]);
            const int e = __builtin_amdgcn_readfirstlane(row_ptr[i + 1]);
            int p = s;
            for (; p + 4 <= e; p += 4) {  // 4-deep MLP on the gathers
                const int j0 = colv[p], j1 = colv[p + 1], j2 = colv[p + 2], j3 = colv[p + 3];
                const float v0 = valv[p], v1 = valv[p + 1], v2 = valv[p + 2], v3 = valv[p + 3];
                if (lane < IN_W) {
                    const float g0 = h[j0 * IN_W + lane];
                    const float g1 = h[j1 * IN_W + lane];
                    const float g2 = h[j2 * IN_W + lane];
                    const float g3 = h[j3 * IN_W + lane];
                    acc += v0 * g0; acc += v1 * g1; acc += v2 * g2; acc += v3 * g3;
                }
            }
            for (; p < e; ++p) {
                const int j = colv[p]; const float v = valv[p];
                if (lane < IN_W) acc += v * h[j * IN_W + lane];
            }
        }
        if (lane < IN_W) aggT[lane][rl] = acc;
    }
    __syncthreads();

    // phase 2: [64 x IN_W] @ [IN_W x OUT_W], 4x4 (or 4x2) register tile per thread
    constexpr int CPT = (OUT_W >= 4) ? 4 : OUT_W;
    constexpr int TXN = OUT_W / CPT;
    const int tx = tid % TXN;
    const int ty = tid / TXN;
    if (ty < TILE_R / 4) {
        float c[4][CPT];
#pragma unroll
        for (int r = 0; r < 4; ++r)
#pragma unroll
            for (int q = 0; q < CPT; ++q) c[r][q] = 0.f;

#pragma unroll 4
        for (int k = 0; k < IN_W; ++k) {
            const float4 a = *(const float4*)&aggT[k][ty * 4];
            float wv[CPT];
            if constexpr (CPT == 4) {
                const float4 wq = *(const float4*)&Wl[k][tx * 4];
                wv[0] = wq.x; wv[1] = wq.y; wv[2] = wq.z; wv[3] = wq.w;
            } else {
#pragma unroll
                for (int q = 0; q < CPT; ++q) wv[q] = Wl[k][tx * CPT + q];
            }
#pragma unroll
            for (int q = 0; q < CPT; ++q) {
                c[0][q] += a.x * wv[q];
                c[1][q] += a.y * wv[q];
                c[2][q] += a.z * wv[q];
                c[3][q] += a.w * wv[q];
            }
        }
        float bq[CPT];
#pragma unroll
        for (int q = 0; q < CPT; ++q) bq[q] = HAS_BIAS ? bias[tx * CPT + q] : 0.f;
#pragma unroll
        for (int r = 0; r < 4; ++r) {
            const int i = tile0 + ty * 4 + r;
            if (i < NN) {
#pragma unroll
                for (int q = 0; q < CPT; ++q) {
                    float o = c[r][q] + bq[q];
                    if (HAS_ADD) o += addsrc[i * OUT_W + tx * CPT + q];
                    if (RELU) o = fmaxf(o, 0.f);
                    out[i * OUT_W + tx * CPT + q] = o;
                }
            }
        }
    }
}

// ---------------- driver ----------------

extern "C" void kernel_launch(void* const* d_in, const int* in_sizes, int n_in,
                              void* d_out, int out_size, void* d_ws, size_t ws_size,
                              hipStream_t stream) {
    const float* x   = (const float*)d_in[0];
    const float* Wp  = (const float*)d_in[1];
    const float* bp  = (const float*)d_in[2];
    const float* Wr  = (const float*)d_in[3];
    const float* br  = (const float*)d_in[4];
    const float* W11 = (const float*)d_in[5];
    const float* b11 = (const float*)d_in[6];
    const float* W12 = (const float*)d_in[7];
    const float* b12 = (const float*)d_in[8];
    const float* W21 = (const float*)d_in[9];
    const float* b21 = (const float*)d_in[10];
    const float* W22 = (const float*)d_in[11];
    const float* b22 = (const float*)d_in[12];
    const float* Wh1 = (const float*)d_in[13];
    const float* bh1 = (const float*)d_in[14];
    const float* Wh2 = (const float*)d_in[15];
    const float* bh2 = (const float*)d_in[16];
    const float* Wh3 = (const float*)d_in[17];
    const float* bh3 = (const float*)d_in[18];
    const int* edge  = (const int*)d_in[19];
    // iters_to_do: fixed at 5 (single-element input; constant per harness contract)
    const int* srcA = edge;
    const int* dstA = edge + NE;
    float* outp = (float*)d_out;

    char* p = (char*)d_ws;
    auto carve = [&](size_t bytes) {
        char* r = p;
        p += (bytes + 255) & ~(size_t)255;
        return r;
    };
    int*   cnt  = (int*)carve(NN * 4);
    int*   fil  = (int*)carve(NN * 4);
    int*   rptr = (int*)carve((NN + 1) * 4);
    float* dis  = (float*)carve(NN * 4);
    int*   colv = (int*)carve((size_t)NE * 4);
    float* valv = (float*)carve((size_t)NE * 4);
    float* ax   = (float*)carve((size_t)NN * 3 * 4);
    float* xr   = (float*)carve((size_t)NN * 64 * 4);
    float* bt   = (float*)carve((size_t)NN * 64 * 4);
    float* bu   = (float*)carve((size_t)NN * 64 * 4);
    float* bv   = (float*)carve((size_t)NN * 64 * 4);
    float* bw   = (float*)carve((size_t)NN * 64 * 4);

    hipMemsetAsync(cnt, 0, NN * 4, stream);
    hipMemsetAsync(fil, 0, NN * 4, stream);
    count_kernel<<<(NE + 255) / 256, 256, 0, stream>>>(dstA, cnt);
    dis_kernel<<<(NN + 255) / 256, 256, 0, stream>>>(cnt, dis);
    scan_kernel<<<1, 1024, 0, stream>>>(cnt, rptr);
    fill_kernel<<<(NE + 255) / 256, 256, 0, stream>>>(srcA, dstA, rptr, fil, dis, colv, valv);
    aggx_kernel<<<(NN + 255) / 256, 256, 0, stream>>>(x, rptr, colv, valv, dis, ax);
    proj_kernel<<<(NN * 64 + 255) / 256, 256, 0, stream>>>(ax, Wp, bp, Wr, br, bt, xr);

    const int GB = (NN + 63) / 64;
    for (int it = 0; it < 5; ++it) {
        // recall: t = (Ahat t) @ Wr_top + xr        (xr already holds ax@Wr_bot + br)
        gcn_kernel<64, 64, false, true, false><<<GB, 256, 0, stream>>>(
            bt, Wr, nullptr, xr, rptr, colv, valv, dis, bu);
        // block1: o = relu(gcn(t, W11, b11))
        gcn_kernel<64, 64, true, false, true><<<GB, 256, 0, stream>>>(
            bu, W11, b11, nullptr, rptr, colv, valv, dis, bv);
        //         t = relu(gcn(o, W12, b12) + t)
        gcn_kernel<64, 64, true, true, true><<<GB, 256, 0, stream>>>(
            bv, W12, b12, bu, rptr, colv, valv, dis, bw);
        // block2
        gcn_kernel<64, 64, true, false, true><<<GB, 256, 0, stream>>>(
            bw, W21, b21, nullptr, rptr, colv, valv, dis, bv);
        gcn_kernel<64, 64, true, true, true><<<GB, 256, 0, stream>>>(
            bv, W22, b22, bw, rptr, colv, valv, dis, bt);
    }
    // head
    gcn_kernel<64, 32, true, false, true><<<GB, 256, 0, stream>>>(
        bt, Wh1, bh1, nullptr, rptr, colv, valv, dis, bu);
    gcn_kernel<32, 8, true, false, true><<<GB, 256, 0, stream>>>(
        bu, Wh2, bh2, nullptr, rptr, colv, valv, dis, bv);
    gcn_kernel<8, 2, false, false, true><<<GB, 256, 0, stream>>>(
        bv, Wh3, bh3, nullptr, rptr, colv, valv, dis, outp);
}

// Round 2
// 2395.702 us; speedup vs baseline: 1.3079x; 1.3079x over previous
//
#include <hip/hip_runtime.h>

#define NN 100000
#define NE 1600000
#define CHUNK 1024
#define NCHUNK ((NN + CHUNK - 1) / CHUNK)

// ---------------- preprocessing ----------------

__global__ void count_kernel(const int* __restrict__ dst, int* __restrict__ cnt) {
    int e = blockIdx.x * blockDim.x + threadIdx.x;
    if (e < NE) atomicAdd(&cnt[dst[e]], 1);
}

__global__ void dis_kernel(const int* __restrict__ cnt, float* __restrict__ dis) {
    int i = blockIdx.x * blockDim.x + threadIdx.x;
    if (i < NN) dis[i] = rsqrtf((float)(cnt[i] + 1));  // +1 self loop
}

// hierarchical exclusive scan of (cnt[i]+1)  [self-loop included in CSR]
__global__ __launch_bounds__(256) void scan1_kernel(const int* __restrict__ cnt,
                                                    int* __restrict__ row_ptr,
                                                    int* __restrict__ sums) {
    __shared__ int sdata[256];
    const int b = blockIdx.x, t = threadIdx.x;
    const int base = b * CHUNK + t * 4;
    int v0 = (base + 0 < NN) ? cnt[base + 0] + 1 : 0;
    int v1 = (base + 1 < NN) ? cnt[base + 1] + 1 : 0;
    int v2 = (base + 2 < NN) ? cnt[base + 2] + 1 : 0;
    int v3 = (base + 3 < NN) ? cnt[base + 3] + 1 : 0;
    const int s = v0 + v1 + v2 + v3;
    sdata[t] = s;
    __syncthreads();
    for (int off = 1; off < 256; off <<= 1) {
        int xv = (t >= off) ? sdata[t - off] : 0;
        __syncthreads();
        sdata[t] += xv;
        __syncthreads();
    }
    const int excl = sdata[t] - s;
    if (base + 0 < NN) row_ptr[base + 0] = excl;
    if (base + 1 < NN) row_ptr[base + 1] = excl + v0;
    if (base + 2 < NN) row_ptr[base + 2] = excl + v0 + v1;
    if (base + 3 < NN) row_ptr[base + 3] = excl + v0 + v1 + v2;
    if (t == 255) sums[b] = sdata[255];
}

__global__ __launch_bounds__(128) void scan2_kernel(int* __restrict__ sums,
                                                    int* __restrict__ row_ptr) {
    __shared__ int sd[128];
    const int t = threadIdx.x;
    const int v = (t < NCHUNK) ? sums[t] : 0;
    sd[t] = v;
    __syncthreads();
    for (int off = 1; off < 128; off <<= 1) {
        int xv = (t >= off) ? sd[t - off] : 0;
        __syncthreads();
        sd[t] += xv;
        __syncthreads();
    }
    if (t < NCHUNK) sums[t] = sd[t] - v;  // exclusive chunk base
    if (t == 127) row_ptr[NN] = sd[127];
}

__global__ void scan3_kernel(int* __restrict__ row_ptr, const int* __restrict__ sums) {
    int i = blockIdx.x * blockDim.x + threadIdx.x;
    if (i < NN) row_ptr[i] += sums[i >> 10];
}

__global__ void fill_kernel(const int* __restrict__ src, const int* __restrict__ dst,
                            const int* __restrict__ row_ptr, int* __restrict__ fil,
                            const float* __restrict__ dis,
                            int* __restrict__ col, float* __restrict__ val) {
    int e = blockIdx.x * blockDim.x + threadIdx.x;
    if (e >= NE) return;
    int d = dst[e], s = src[e];
    int pos = atomicAdd(&fil[d], 1);
    int o = row_ptr[d] + pos;
    col[o] = s;
    val[o] = dis[s] * dis[d];
}

__global__ void selffill_kernel(const int* __restrict__ row_ptr, const int* __restrict__ cnt,
                                const float* __restrict__ dis,
                                int* __restrict__ col, float* __restrict__ val) {
    int i = blockIdx.x * blockDim.x + threadIdx.x;
    if (i >= NN) return;
    int o = row_ptr[i] + cnt[i];  // self edge goes last in the row
    col[o] = i;
    float d = dis[i];
    val[o] = d * d;
}

// ax = Ahat @ x   (width 3; CSR already includes self loop)
__global__ void aggx_kernel(const float* __restrict__ x, const int* __restrict__ row_ptr,
                            const int* __restrict__ col, const float* __restrict__ val,
                            float* __restrict__ ax) {
    int i = blockIdx.x * blockDim.x + threadIdx.x;
    if (i >= NN) return;
    float a0 = 0.f, a1 = 0.f, a2 = 0.f;
    int e = row_ptr[i + 1];
    for (int p = row_ptr[i]; p < e; ++p) {
        int j = col[p]; float v = val[p];
        a0 += v * x[j * 3 + 0];
        a1 += v * x[j * 3 + 1];
        a2 += v * x[j * 3 + 2];
    }
    ax[i * 3 + 0] = a0; ax[i * 3 + 1] = a1; ax[i * 3 + 2] = a2;
}

// t0 = relu(ax @ Wp + bp)   and   xr = ax @ Wr[64:67,:] + br
__global__ void proj_kernel(const float* __restrict__ ax,
                            const float* __restrict__ Wp, const float* __restrict__ bp,
                            const float* __restrict__ Wr, const float* __restrict__ br,
                            float* __restrict__ t0, float* __restrict__ xr) {
    int g = blockIdx.x * blockDim.x + threadIdx.x;
    if (g >= NN * 64) return;
    int i = g >> 6, c = g & 63;
    float a0 = ax[i * 3 + 0], a1 = ax[i * 3 + 1], a2 = ax[i * 3 + 2];
    float tp = a0 * Wp[c] + a1 * Wp[64 + c] + a2 * Wp[128 + c] + bp[c];
    t0[g] = fmaxf(tp, 0.f);
    xr[g] = a0 * Wr[64 * 64 + c] + a1 * Wr[65 * 64 + c] + a2 * Wr[66 * 64 + c] + br[c];
}

// ---------------- fused GCN: out = act( (Ahat h) @ W + bias + add ) ----------------
// Phase 1: lane = (edge-slot, feature-quad); each lane gathers a float4, so one
// global_load_dwordx4 fetches SLOTS whole rows; 2x manual unroll => 2*SLOTS edges
// in flight. Slot partials combine via shfl_xor. Self loop is a CSR edge.
// Phase 2: [64 x IN_W] @ [IN_W x OUT_W] with W read from global (L1-resident).

template <int IN_W, int OUT_W, bool RELU, bool HAS_ADD, bool HAS_BIAS>
__global__ __launch_bounds__(256, 6) void gcn_kernel(
    const float* __restrict__ h, const float* __restrict__ Wg,
    const float* __restrict__ bias, const float* __restrict__ addsrc,
    const int* __restrict__ row_ptr, const int* __restrict__ colv,
    const float* __restrict__ valv, float* __restrict__ out) {
    constexpr int TILE_R = 64;
    constexpr int QUADS = IN_W / 4;   // float4 lanes per row
    constexpr int SLOTS = 64 / QUADS; // edges gathered per wave instruction
    constexpr int STR = IN_W + 4;     // row pad: 16B-aligned, breaks pow2 stride
    __shared__ __align__(16) float aggT[TILE_R][STR];

    const int tid = threadIdx.x;
    const int tile0 = blockIdx.x * TILE_R;
    const int wave = tid >> 6;
    const int lane = tid & 63;
    const int slot = lane / QUADS;
    const int fq = lane - slot * QUADS;

    for (int rr = 0; rr < 16; ++rr) {
        const int rl = (wave << 4) + rr;
        const int i = tile0 + rl;
        float4 a0 = make_float4(0.f, 0.f, 0.f, 0.f);
        float4 a1 = make_float4(0.f, 0.f, 0.f, 0.f);
        if (i < NN) {
            const int s = __builtin_amdgcn_readfirstlane(row_ptr[i]);
            const int e = __builtin_amdgcn_readfirstlane(row_ptr[i + 1]);
            for (int p = s; p < e; p += 2 * SLOTS) {
                const int q0 = p + slot;
                const int q1 = q0 + SLOTS;
                const bool k0 = q0 < e, k1 = q1 < e;
                const int j0 = k0 ? colv[q0] : 0;
                const float v0 = k0 ? valv[q0] : 0.f;
                const int j1 = k1 ? colv[q1] : 0;
                const float v1 = k1 ? valv[q1] : 0.f;
                const float4 g0 = *(const float4*)(h + j0 * IN_W + (fq << 2));
                const float4 g1 = *(const float4*)(h + j1 * IN_W + (fq << 2));
                a0.x += v0 * g0.x; a0.y += v0 * g0.y; a0.z += v0 * g0.z; a0.w += v0 * g0.w;
                a1.x += v1 * g1.x; a1.y += v1 * g1.y; a1.z += v1 * g1.z; a1.w += v1 * g1.w;
            }
        }
        float4 acc;
        acc.x = a0.x + a1.x; acc.y = a0.y + a1.y;
        acc.z = a0.z + a1.z; acc.w = a0.w + a1.w;
#pragma unroll
        for (int m = QUADS; m < 64; m <<= 1) {
            acc.x += __shfl_xor(acc.x, m, 64);
            acc.y += __shfl_xor(acc.y, m, 64);
            acc.z += __shfl_xor(acc.z, m, 64);
            acc.w += __shfl_xor(acc.w, m, 64);
        }
        if (slot == 0) *(float4*)&aggT[rl][fq << 2] = acc;
    }
    __syncthreads();

    // phase 2
    constexpr int CPT = (OUT_W >= 4) ? 4 : OUT_W;
    constexpr int TXN = OUT_W / CPT;
    const int tx = tid % TXN;
    const int ty = tid / TXN;
    if (ty < TILE_R / 4) {
        float c[4][CPT];
#pragma unroll
        for (int r = 0; r < 4; ++r)
#pragma unroll
            for (int q = 0; q < CPT; ++q) c[r][q] = 0.f;

#pragma unroll 2
        for (int k4 = 0; k4 < IN_W / 4; ++k4) {
            float4 av[4];
#pragma unroll
            for (int r = 0; r < 4; ++r) av[r] = *(const float4*)&aggT[ty * 4 + r][k4 << 2];
#pragma unroll
            for (int kk = 0; kk < 4; ++kk) {
                float wv[CPT];
                if constexpr (CPT == 4) {
                    const float4 w4 = *(const float4*)(Wg + ((k4 << 2) + kk) * OUT_W + (tx << 2));
                    wv[0] = w4.x; wv[1] = w4.y; wv[2] = w4.z; wv[3] = w4.w;
                } else {
#pragma unroll
                    for (int q = 0; q < CPT; ++q)
                        wv[q] = Wg[((k4 << 2) + kk) * OUT_W + tx * CPT + q];
                }
#pragma unroll
                for (int r = 0; r < 4; ++r) {
                    const float ar = ((const float*)&av[r])[kk];
#pragma unroll
                    for (int q = 0; q < CPT; ++q) c[r][q] += ar * wv[q];
                }
            }
        }
        float bq[CPT];
#pragma unroll
        for (int q = 0; q < CPT; ++q) bq[q] = HAS_BIAS ? bias[tx * CPT + q] : 0.f;
#pragma unroll
        for (int r = 0; r < 4; ++r) {
            const int i = tile0 + ty * 4 + r;
            if (i < NN) {
                if constexpr (CPT == 4) {
                    float4 o4;
                    float* o = (float*)&o4;
#pragma unroll
                    for (int q = 0; q < 4; ++q) o[q] = c[r][q] + bq[q];
                    if (HAS_ADD) {
                        const float4 ad = *(const float4*)(addsrc + i * OUT_W + (tx << 2));
                        o4.x += ad.x; o4.y += ad.y; o4.z += ad.z; o4.w += ad.w;
                    }
                    if (RELU) {
                        o4.x = fmaxf(o4.x, 0.f); o4.y = fmaxf(o4.y, 0.f);
                        o4.z = fmaxf(o4.z, 0.f); o4.w = fmaxf(o4.w, 0.f);
                    }
                    *(float4*)(out + i * OUT_W + (tx << 2)) = o4;
                } else {
#pragma unroll
                    for (int q = 0; q < CPT; ++q) {
                        float o = c[r][q] + bq[q];
                        if (HAS_ADD) o += addsrc[i * OUT_W + tx * CPT + q];
                        if (RELU) o = fmaxf(o, 0.f);
                        out[i * OUT_W + tx * CPT + q] = o;
                    }
                }
            }
        }
    }
}

// ---------------- driver ----------------

extern "C" void kernel_launch(void* const* d_in, const int* in_sizes, int n_in,
                              void* d_out, int out_size, void* d_ws, size_t ws_size,
                              hipStream_t stream) {
    const float* x   = (const float*)d_in[0];
    const float* Wp  = (const float*)d_in[1];
    const float* bp  = (const float*)d_in[2];
    const float* Wr  = (const float*)d_in[3];
    const float* br  = (const float*)d_in[4];
    const float* W11 = (const float*)d_in[5];
    const float* b11 = (const float*)d_in[6];
    const float* W12 = (const float*)d_in[7];
    const float* b12 = (const float*)d_in[8];
    const float* W21 = (const float*)d_in[9];
    const float* b21 = (const float*)d_in[10];
    const float* W22 = (const float*)d_in[11];
    const float* b22 = (const float*)d_in[12];
    const float* Wh1 = (const float*)d_in[13];
    const float* bh1 = (const float*)d_in[14];
    const float* Wh2 = (const float*)d_in[15];
    const float* bh2 = (const float*)d_in[16];
    const float* Wh3 = (const float*)d_in[17];
    const float* bh3 = (const float*)d_in[18];
    const int* edge  = (const int*)d_in[19];
    const int* srcA = edge;
    const int* dstA = edge + NE;
    float* outp = (float*)d_out;

    char* p = (char*)d_ws;
    auto carve = [&](size_t bytes) {
        char* r = p;
        p += (bytes + 255) & ~(size_t)255;
        return r;
    };
    int*   cnt  = (int*)carve(NN * 4);
    int*   fil  = (int*)carve(NN * 4);
    int*   rptr = (int*)carve((NN + 1) * 4);
    float* dis  = (float*)carve(NN * 4);
    int*   sums = (int*)carve(128 * 4);
    int*   colv = (int*)carve((size_t)(NE + NN) * 4);
    float* valv = (float*)carve((size_t)(NE + NN) * 4);
    float* ax   = (float*)carve((size_t)NN * 3 * 4);
    float* xr   = (float*)carve((size_t)NN * 64 * 4);
    float* bt   = (float*)carve((size_t)NN * 64 * 4);
    float* bu   = (float*)carve((size_t)NN * 64 * 4);
    float* bv   = (float*)carve((size_t)NN * 64 * 4);
    float* bw   = (float*)carve((size_t)NN * 64 * 4);

    hipMemsetAsync(cnt, 0, NN * 4, stream);
    hipMemsetAsync(fil, 0, NN * 4, stream);
    count_kernel<<<(NE + 255) / 256, 256, 0, stream>>>(dstA, cnt);
    dis_kernel<<<(NN + 255) / 256, 256, 0, stream>>>(cnt, dis);
    scan1_kernel<<<NCHUNK, 256, 0, stream>>>(cnt, rptr, sums);
    scan2_kernel<<<1, 128, 0, stream>>>(sums, rptr);
    scan3_kernel<<<(NN + 255) / 256, 256, 0, stream>>>(rptr, sums);
    fill_kernel<<<(NE + 255) / 256, 256, 0, stream>>>(srcA, dstA, rptr, fil, dis, colv, valv);
    selffill_kernel<<<(NN + 255) / 256, 256, 0, stream>>>(rptr, cnt, dis, colv, valv);
    aggx_kernel<<<(NN + 255) / 256, 256, 0, stream>>>(x, rptr, colv, valv, ax);
    proj_kernel<<<(NN * 64 + 255) / 256, 256, 0, stream>>>(ax, Wp, bp, Wr, br, bt, xr);

    const int GB = (NN + 63) / 64;
    for (int it = 0; it < 5; ++it) {
        gcn_kernel<64, 64, false, true, false><<<GB, 256, 0, stream>>>(
            bt, Wr, nullptr, xr, rptr, colv, valv, bu);
        gcn_kernel<64, 64, true, false, true><<<GB, 256, 0, stream>>>(
            bu, W11, b11, nullptr, rptr, colv, valv, bv);
        gcn_kernel<64, 64, true, true, true><<<GB, 256, 0, stream>>>(
            bv, W12, b12, bu, rptr, colv, valv, bw);
        gcn_kernel<64, 64, true, false, true><<<GB, 256, 0, stream>>>(
            bw, W21, b21, nullptr, rptr, colv, valv, bv);
        gcn_kernel<64, 64, true, true, true><<<GB, 256, 0, stream>>>(
            bv, W22, b22, bw, rptr, colv, valv, bt);
    }
    gcn_kernel<64, 32, true, false, true><<<GB, 256, 0, stream>>>(
        bt, Wh1, bh1, nullptr, rptr, colv, valv, bu);
    gcn_kernel<32, 8, true, false, true><<<GB, 256, 0, stream>>>(
        bu, Wh2, bh2, nullptr, rptr, colv, valv, bv);
    gcn_kernel<8, 2, false, false, true><<<GB, 256, 0, stream>>>(
        bv, Wh3, bh3, nullptr, rptr, colv, valv, outp);
}

// Round 3
// 1836.206 us; speedup vs baseline: 1.7064x; 1.3047x over previous
//
#include <hip/hip_runtime.h>
#include <hip/hip_fp16.h>

#define NN 100000
#define NE 1600000
#define CHUNK 1024
#define NCHUNK ((NN + CHUNK - 1) / CHUNK)

// ---------------- preprocessing ----------------

__global__ void count_kernel(const int* __restrict__ dst, int* __restrict__ cnt) {
    int e = blockIdx.x * blockDim.x + threadIdx.x;
    if (e < NE) atomicAdd(&cnt[dst[e]], 1);
}

// dis[i] = rsqrt(deg_i+1);  xs = dis-prescaled x rows (for aggx)
__global__ void dis_xs_kernel(const int* __restrict__ cnt, const float* __restrict__ x,
                              float* __restrict__ dis, float* __restrict__ xs) {
    int i = blockIdx.x * blockDim.x + threadIdx.x;
    if (i >= NN) return;
    float d = rsqrtf((float)(cnt[i] + 1));
    dis[i] = d;
    xs[i * 3 + 0] = d * x[i * 3 + 0];
    xs[i * 3 + 1] = d * x[i * 3 + 1];
    xs[i * 3 + 2] = d * x[i * 3 + 2];
}

// hierarchical exclusive scan of (cnt[i]+1)  [self-loop included in CSR]
__global__ __launch_bounds__(256) void scan1_kernel(const int* __restrict__ cnt,
                                                    int* __restrict__ row_ptr,
                                                    int* __restrict__ sums) {
    __shared__ int sdata[256];
    const int b = blockIdx.x, t = threadIdx.x;
    const int base = b * CHUNK + t * 4;
    int v0 = (base + 0 < NN) ? cnt[base + 0] + 1 : 0;
    int v1 = (base + 1 < NN) ? cnt[base + 1] + 1 : 0;
    int v2 = (base + 2 < NN) ? cnt[base + 2] + 1 : 0;
    int v3 = (base + 3 < NN) ? cnt[base + 3] + 1 : 0;
    const int s = v0 + v1 + v2 + v3;
    sdata[t] = s;
    __syncthreads();
    for (int off = 1; off < 256; off <<= 1) {
        int xv = (t >= off) ? sdata[t - off] : 0;
        __syncthreads();
        sdata[t] += xv;
        __syncthreads();
    }
    const int excl = sdata[t] - s;
    if (base + 0 < NN) row_ptr[base + 0] = excl;
    if (base + 1 < NN) row_ptr[base + 1] = excl + v0;
    if (base + 2 < NN) row_ptr[base + 2] = excl + v0 + v1;
    if (base + 3 < NN) row_ptr[base + 3] = excl + v0 + v1 + v2;
    if (t == 255) sums[b] = sdata[255];
}

__global__ __launch_bounds__(128) void scan2_kernel(int* __restrict__ sums,
                                                    int* __restrict__ row_ptr) {
    __shared__ int sd[128];
    const int t = threadIdx.x;
    const int v = (t < NCHUNK) ? sums[t] : 0;
    sd[t] = v;
    __syncthreads();
    for (int off = 1; off < 128; off <<= 1) {
        int xv = (t >= off) ? sd[t - off] : 0;
        __syncthreads();
        sd[t] += xv;
        __syncthreads();
    }
    if (t < NCHUNK) sums[t] = sd[t] - v;
    if (t == 127) row_ptr[NN] = sd[127];
}

__global__ void scan3_kernel(int* __restrict__ row_ptr, const int* __restrict__ sums) {
    int i = blockIdx.x * blockDim.x + threadIdx.x;
    if (i < NN) row_ptr[i] += sums[i >> 10];
}

// CSR fill: col only (4B scatter per edge; val folded into prescaled rows)
__global__ void fill_kernel(const int* __restrict__ src, const int* __restrict__ dst,
                            const int* __restrict__ row_ptr, int* __restrict__ fil,
                            int* __restrict__ col) {
    int e = blockIdx.x * blockDim.x + threadIdx.x;
    if (e >= NE) return;
    int d = dst[e];
    int pos = atomicAdd(&fil[d], 1);
    col[row_ptr[d] + pos] = src[e];
}

__global__ void selffill_kernel(const int* __restrict__ row_ptr, const int* __restrict__ cnt,
                                int* __restrict__ col) {
    int i = blockIdx.x * blockDim.x + threadIdx.x;
    if (i >= NN) return;
    col[row_ptr[i] + cnt[i]] = i;  // self edge last in the row
}

// ax = Ahat @ x = dis_i * sum_j xs[j]   (CSR includes self loop)
__global__ void aggx_kernel(const float* __restrict__ xs, const int* __restrict__ row_ptr,
                            const int* __restrict__ col, const float* __restrict__ dis,
                            float* __restrict__ ax) {
    int i = blockIdx.x * blockDim.x + threadIdx.x;
    if (i >= NN) return;
    float a0 = 0.f, a1 = 0.f, a2 = 0.f;
    int e = row_ptr[i + 1];
    for (int p = row_ptr[i]; p < e; ++p) {
        int j = col[p];
        a0 += xs[j * 3 + 0];
        a1 += xs[j * 3 + 1];
        a2 += xs[j * 3 + 2];
    }
    float d = dis[i];
    ax[i * 3 + 0] = d * a0; ax[i * 3 + 1] = d * a1; ax[i * 3 + 2] = d * a2;
}

// t16 = fp16(dis * relu(ax @ Wp + bp));  xr = ax @ Wr[64:67,:] + br
__global__ void proj_kernel(const float* __restrict__ ax,
                            const float* __restrict__ Wp, const float* __restrict__ bp,
                            const float* __restrict__ Wr, const float* __restrict__ br,
                            const float* __restrict__ dis,
                            __half* __restrict__ t16, float* __restrict__ xr) {
    int g = blockIdx.x * blockDim.x + threadIdx.x;
    if (g >= NN * 64) return;
    int i = g >> 6, c = g & 63;
    float a0 = ax[i * 3 + 0], a1 = ax[i * 3 + 1], a2 = ax[i * 3 + 2];
    float tp = fmaxf(a0 * Wp[c] + a1 * Wp[64 + c] + a2 * Wp[128 + c] + bp[c], 0.f);
    t16[g] = __float2half(tp * dis[i]);
    xr[g] = a0 * Wr[64 * 64 + c] + a1 * Wr[65 * 64 + c] + a2 * Wr[66 * 64 + c] + br[c];
}

// ---------------- fused GCN ----------------
// h16 rows are fp16, pre-scaled by dis[j].  agg_i = dis_i * sum_{j in row} h16[j].
// Phase 1: lane = slot*QUADS + fq; each lane loads 16B (8 halves) of a row; one
// wave instruction gathers SLOTS rows; 2x unroll => 2*SLOTS edges in flight.
// Tail handled branchlessly: index clamped to e-1, FMA masked.
// Phase 2: [64 x IN_W] fp32 @ [IN_W x OUT_W] with W from global (L1-resident);
// writes fp32 (residual path) and/or dis-prescaled fp16 (next gather) outputs.

__device__ __forceinline__ void acc8_fma(float* a, float m, uint4 r) {
    union { uint4 u; __half2 h[4]; } cv;
    cv.u = r;
#pragma unroll
    for (int t = 0; t < 4; ++t) {
        float2 f = __half22float2(cv.h[t]);
        a[2 * t]     = fmaf(m, f.x, a[2 * t]);
        a[2 * t + 1] = fmaf(m, f.y, a[2 * t + 1]);
    }
}

template <int IN_W, int OUT_W, bool RELU, bool HAS_ADD, bool HAS_BIAS, bool W32, bool W16>
__global__ __launch_bounds__(256, 6) void gcn_kernel(
    const __half* __restrict__ h16, const float* __restrict__ Wg,
    const float* __restrict__ bias, const float* __restrict__ addsrc,
    const int* __restrict__ row_ptr, const int* __restrict__ colv,
    const float* __restrict__ dis,
    float* __restrict__ out32, __half* __restrict__ out16) {
    constexpr int TILE_R = 64;
    constexpr int QUADS = IN_W / 8;      // lanes per row (16B = 8 halves each)
    constexpr int SLOTS = 64 / QUADS;    // rows gathered per wave instruction
    constexpr int STR = IN_W + 4;
    __shared__ __align__(16) float aggT[TILE_R][STR];

    const int tid = threadIdx.x;
    const int tile0 = blockIdx.x * TILE_R;
    const int wave = tid >> 6;
    const int lane = tid & 63;
    const int fq = lane & (QUADS - 1);
    const int slot = lane / QUADS;

    for (int rr = 0; rr < 16; ++rr) {
        const int rl = (wave << 4) + rr;
        const int i = tile0 + rl;
        float a0[8], a1[8];
#pragma unroll
        for (int t = 0; t < 8; ++t) { a0[t] = 0.f; a1[t] = 0.f; }
        float di = 0.f;
        if (i < NN) {
            di = dis[i];
            const int s = __builtin_amdgcn_readfirstlane(row_ptr[i]);
            const int e = __builtin_amdgcn_readfirstlane(row_ptr[i + 1]);
            const int last = e - 1;
            for (int p = s; p < e; p += 2 * SLOTS) {
                const int q0 = p + slot;
                const int q1 = q0 + SLOTS;
                const float m0 = (q0 < e) ? 1.f : 0.f;
                const float m1 = (q1 < e) ? 1.f : 0.f;
                const int j0 = colv[min(q0, last)];
                const int j1 = colv[min(q1, last)];
                const uint4 r0 = *(const uint4*)(h16 + (size_t)j0 * IN_W + (fq << 3));
                const uint4 r1 = *(const uint4*)(h16 + (size_t)j1 * IN_W + (fq << 3));
                acc8_fma(a0, m0, r0);
                acc8_fma(a1, m1, r1);
            }
        }
        float acc[8];
#pragma unroll
        for (int t = 0; t < 8; ++t) acc[t] = a0[t] + a1[t];
#pragma unroll
        for (int m = QUADS; m < 64; m <<= 1) {
#pragma unroll
            for (int t = 0; t < 8; ++t) acc[t] += __shfl_xor(acc[t], m, 64);
        }
        if (slot == 0) {
#pragma unroll
            for (int t = 0; t < 8; ++t) acc[t] *= di;
            *(float4*)&aggT[rl][(fq << 3)]     = make_float4(acc[0], acc[1], acc[2], acc[3]);
            *(float4*)&aggT[rl][(fq << 3) + 4] = make_float4(acc[4], acc[5], acc[6], acc[7]);
        }
    }
    __syncthreads();

    // phase 2
    constexpr int CPT = (OUT_W >= 4) ? 4 : OUT_W;
    constexpr int TXN = OUT_W / CPT;
    const int tx = tid % TXN;
    const int ty = tid / TXN;
    if (ty < TILE_R / 4) {
        float c[4][CPT];
#pragma unroll
        for (int r = 0; r < 4; ++r)
#pragma unroll
            for (int q = 0; q < CPT; ++q) c[r][q] = 0.f;

#pragma unroll 2
        for (int k4 = 0; k4 < IN_W / 4; ++k4) {
            float4 av[4];
#pragma unroll
            for (int r = 0; r < 4; ++r) av[r] = *(const float4*)&aggT[ty * 4 + r][k4 << 2];
#pragma unroll
            for (int kk = 0; kk < 4; ++kk) {
                float wv[CPT];
                if constexpr (CPT == 4) {
                    const float4 w4 = *(const float4*)(Wg + ((k4 << 2) + kk) * OUT_W + (tx << 2));
                    wv[0] = w4.x; wv[1] = w4.y; wv[2] = w4.z; wv[3] = w4.w;
                } else {
#pragma unroll
                    for (int q = 0; q < CPT; ++q)
                        wv[q] = Wg[((k4 << 2) + kk) * OUT_W + tx * CPT + q];
                }
#pragma unroll
                for (int r = 0; r < 4; ++r) {
                    const float ar = ((const float*)&av[r])[kk];
#pragma unroll
                    for (int q = 0; q < CPT; ++q) c[r][q] += ar * wv[q];
                }
            }
        }
        float bq[CPT];
#pragma unroll
        for (int q = 0; q < CPT; ++q) bq[q] = HAS_BIAS ? bias[tx * CPT + q] : 0.f;
#pragma unroll
        for (int r = 0; r < 4; ++r) {
            const int i = tile0 + ty * 4 + r;
            if (i < NN) {
                float o[CPT];
#pragma unroll
                for (int q = 0; q < CPT; ++q) o[q] = c[r][q] + bq[q];
                if constexpr (HAS_ADD) {
#pragma unroll
                    for (int q = 0; q < CPT; ++q) o[q] += addsrc[i * OUT_W + tx * CPT + q];
                }
                if constexpr (RELU) {
#pragma unroll
                    for (int q = 0; q < CPT; ++q) o[q] = fmaxf(o[q], 0.f);
                }
                if constexpr (W32) {
                    if constexpr (CPT == 4) {
                        *(float4*)(out32 + i * OUT_W + (tx << 2)) =
                            make_float4(o[0], o[1], o[2], o[3]);
                    } else {
#pragma unroll
                        for (int q = 0; q < CPT; ++q) out32[i * OUT_W + tx * CPT + q] = o[q];
                    }
                }
                if constexpr (W16) {
                    const float d = dis[i];
                    if constexpr (CPT == 4) {
                        union { uint2 u; __half2 h[2]; } pk;
                        pk.h[0] = __float22half2_rn(make_float2(o[0] * d, o[1] * d));
                        pk.h[1] = __float22half2_rn(make_float2(o[2] * d, o[3] * d));
                        *(uint2*)(out16 + i * OUT_W + (tx << 2)) = pk.u;
                    } else {
#pragma unroll
                        for (int q = 0; q < CPT; ++q)
                            out16[i * OUT_W + tx * CPT + q] = __float2half(o[q] * d);
                    }
                }
            }
        }
    }
}

// ---------------- driver ----------------

extern "C" void kernel_launch(void* const* d_in, const int* in_sizes, int n_in,
                              void* d_out, int out_size, void* d_ws, size_t ws_size,
                              hipStream_t stream) {
    const float* x   = (const float*)d_in[0];
    const float* Wp  = (const float*)d_in[1];
    const float* bp  = (const float*)d_in[2];
    const float* Wr  = (const float*)d_in[3];
    const float* br  = (const float*)d_in[4];
    const float* W11 = (const float*)d_in[5];
    const float* b11 = (const float*)d_in[6];
    const float* W12 = (const float*)d_in[7];
    const float* b12 = (const float*)d_in[8];
    const float* W21 = (const float*)d_in[9];
    const float* b21 = (const float*)d_in[10];
    const float* W22 = (const float*)d_in[11];
    const float* b22 = (const float*)d_in[12];
    const float* Wh1 = (const float*)d_in[13];
    const float* bh1 = (const float*)d_in[14];
    const float* Wh2 = (const float*)d_in[15];
    const float* bh2 = (const float*)d_in[16];
    const float* Wh3 = (const float*)d_in[17];
    const float* bh3 = (const float*)d_in[18];
    const int* edge  = (const int*)d_in[19];
    const int* srcA = edge;
    const int* dstA = edge + NE;
    float* outp = (float*)d_out;

    char* p = (char*)d_ws;
    auto carve = [&](size_t bytes) {
        char* r = p;
        p += (bytes + 255) & ~(size_t)255;
        return r;
    };
    int*    cnt  = (int*)carve(NN * 4);
    int*    fil  = (int*)carve(NN * 4);
    int*    rptr = (int*)carve((NN + 1) * 4);
    float*  dis  = (float*)carve(NN * 4);
    int*    sums = (int*)carve(128 * 4);
    int*    colv = (int*)carve((size_t)(NE + NN + 256) * 4);
    float*  xs   = (float*)carve((size_t)NN * 3 * 4);
    float*  ax   = (float*)carve((size_t)NN * 3 * 4);
    float*  xr   = (float*)carve((size_t)NN * 64 * 4);
    float*  bu32 = (float*)carve((size_t)NN * 64 * 4);
    float*  bw32 = (float*)carve((size_t)NN * 64 * 4);
    __half* bt16 = (__half*)carve((size_t)NN * 64 * 2);
    __half* bu16 = (__half*)carve((size_t)NN * 64 * 2);
    __half* bv16 = (__half*)carve((size_t)NN * 64 * 2);
    __half* bw16 = (__half*)carve((size_t)NN * 64 * 2);

    hipMemsetAsync(cnt, 0, NN * 4, stream);
    hipMemsetAsync(fil, 0, NN * 4, stream);
    count_kernel<<<(NE + 255) / 256, 256, 0, stream>>>(dstA, cnt);
    dis_xs_kernel<<<(NN + 255) / 256, 256, 0, stream>>>(cnt, x, dis, xs);
    scan1_kernel<<<NCHUNK, 256, 0, stream>>>(cnt, rptr, sums);
    scan2_kernel<<<1, 128, 0, stream>>>(sums, rptr);
    scan3_kernel<<<(NN + 255) / 256, 256, 0, stream>>>(rptr, sums);
    fill_kernel<<<(NE + 255) / 256, 256, 0, stream>>>(srcA, dstA, rptr, fil, colv);
    selffill_kernel<<<(NN + 255) / 256, 256, 0, stream>>>(rptr, cnt, colv);
    aggx_kernel<<<(NN + 255) / 256, 256, 0, stream>>>(xs, rptr, colv, dis, ax);
    proj_kernel<<<(NN * 64 + 255) / 256, 256, 0, stream>>>(ax, Wp, bp, Wr, br, dis, bt16, xr);

    const int GB = (NN + 63) / 64;
    for (int it = 0; it < 5; ++it) {
        // recall: bu = (Ahat t)@Wr_top + xr ; write fp32 (residual src) + fp16
        gcn_kernel<64, 64, false, true, false, true, true><<<GB, 256, 0, stream>>>(
            bt16, Wr, nullptr, xr, rptr, colv, dis, bu32, bu16);
        // b1a: bv = relu(gcn(bu, W11, b11))           (gather-only consumer)
        gcn_kernel<64, 64, true, false, true, false, true><<<GB, 256, 0, stream>>>(
            bu16, W11, b11, nullptr, rptr, colv, dis, nullptr, bv16);
        // b1b: bw = relu(gcn(bv, W12, b12) + bu)      (fp32 + fp16)
        gcn_kernel<64, 64, true, true, true, true, true><<<GB, 256, 0, stream>>>(
            bv16, W12, b12, bu32, rptr, colv, dis, bw32, bw16);
        // b2a: bv = relu(gcn(bw, W21, b21))
        gcn_kernel<64, 64, true, false, true, false, true><<<GB, 256, 0, stream>>>(
            bw16, W21, b21, nullptr, rptr, colv, dis, nullptr, bv16);
        // b2b: bt = relu(gcn(bv, W22, b22) + bw)      (gather-only consumer)
        gcn_kernel<64, 64, true, true, true, false, true><<<GB, 256, 0, stream>>>(
            bv16, W22, b22, bw32, rptr, colv, dis, nullptr, bt16);
    }
    // head
    gcn_kernel<64, 32, true, false, true, false, true><<<GB, 256, 0, stream>>>(
        bt16, Wh1, bh1, nullptr, rptr, colv, dis, nullptr, bv16);
    gcn_kernel<32, 8, true, false, true, false, true><<<GB, 256, 0, stream>>>(
        bv16, Wh2, bh2, nullptr, rptr, colv, dis, nullptr, bw16);
    gcn_kernel<8, 2, false, false, true, true, false><<<GB, 256, 0, stream>>>(
        bw16, Wh3, bh3, nullptr, rptr, colv, dis, outp, nullptr);
}

// Round 4
// 1831.136 us; speedup vs baseline: 1.7112x; 1.0028x over previous
//
#include <hip/hip_runtime.h>
#include <hip/hip_fp16.h>

#define NN 100000
#define NE 1600000
#define CHUNK 1024
#define NCHUNK ((NN + CHUNK - 1) / CHUNK)

// ---------------- preprocessing ----------------

__global__ void count_kernel(const int* __restrict__ dst, int* __restrict__ cnt) {
    const int T = NE / 4;
    int t = blockIdx.x * blockDim.x + threadIdx.x;
    if (t >= T) return;
#pragma unroll
    for (int k = 0; k < 4; ++k) atomicAdd(&cnt[dst[t + k * T]], 1);
}

// dis[i] = rsqrt(deg_i+1);  xs = dis-prescaled x rows (for aggx)
__global__ void dis_xs_kernel(const int* __restrict__ cnt, const float* __restrict__ x,
                              float* __restrict__ dis, float* __restrict__ xs) {
    int i = blockIdx.x * blockDim.x + threadIdx.x;
    if (i >= NN) return;
    float d = rsqrtf((float)(cnt[i] + 1));
    dis[i] = d;
    xs[i * 3 + 0] = d * x[i * 3 + 0];
    xs[i * 3 + 1] = d * x[i * 3 + 1];
    xs[i * 3 + 2] = d * x[i * 3 + 2];
}

// hierarchical exclusive scan of (cnt[i]+1)  [self-loop included in CSR]
__global__ __launch_bounds__(256) void scan1_kernel(const int* __restrict__ cnt,
                                                    int* __restrict__ row_ptr,
                                                    int* __restrict__ sums) {
    __shared__ int sdata[256];
    const int b = blockIdx.x, t = threadIdx.x;
    const int base = b * CHUNK + t * 4;
    int v0 = (base + 0 < NN) ? cnt[base + 0] + 1 : 0;
    int v1 = (base + 1 < NN) ? cnt[base + 1] + 1 : 0;
    int v2 = (base + 2 < NN) ? cnt[base + 2] + 1 : 0;
    int v3 = (base + 3 < NN) ? cnt[base + 3] + 1 : 0;
    const int s = v0 + v1 + v2 + v3;
    sdata[t] = s;
    __syncthreads();
    for (int off = 1; off < 256; off <<= 1) {
        int xv = (t >= off) ? sdata[t - off] : 0;
        __syncthreads();
        sdata[t] += xv;
        __syncthreads();
    }
    const int excl = sdata[t] - s;
    if (base + 0 < NN) row_ptr[base + 0] = excl;
    if (base + 1 < NN) row_ptr[base + 1] = excl + v0;
    if (base + 2 < NN) row_ptr[base + 2] = excl + v0 + v1;
    if (base + 3 < NN) row_ptr[base + 3] = excl + v0 + v1 + v2;
    if (t == 255) sums[b] = sdata[255];
}

__global__ __launch_bounds__(128) void scan2_kernel(int* __restrict__ sums,
                                                    int* __restrict__ row_ptr) {
    __shared__ int sd[128];
    const int t = threadIdx.x;
    const int v = (t < NCHUNK) ? sums[t] : 0;
    sd[t] = v;
    __syncthreads();
    for (int off = 1; off < 128; off <<= 1) {
        int xv = (t >= off) ? sd[t - off] : 0;
        __syncthreads();
        sd[t] += xv;
        __syncthreads();
    }
    if (t < NCHUNK) sums[t] = sd[t] - v;
    if (t == 127) row_ptr[NN] = sd[127];
}

__global__ void scan3_kernel(int* __restrict__ row_ptr, const int* __restrict__ sums) {
    int i = blockIdx.x * blockDim.x + threadIdx.x;
    if (i < NN) row_ptr[i] += sums[i >> 10];
}

// CSR fill: col only; 4 independent atomic->store chains per thread
__global__ void fill_kernel(const int* __restrict__ src, const int* __restrict__ dst,
                            const int* __restrict__ row_ptr, int* __restrict__ fil,
                            int* __restrict__ col) {
    const int T = NE / 4;
    int t = blockIdx.x * blockDim.x + threadIdx.x;
    if (t >= T) return;
    int d[4], s[4], pos[4];
#pragma unroll
    for (int k = 0; k < 4; ++k) {
        d[k] = dst[t + k * T];
        s[k] = src[t + k * T];
    }
#pragma unroll
    for (int k = 0; k < 4; ++k) pos[k] = atomicAdd(&fil[d[k]], 1);
#pragma unroll
    for (int k = 0; k < 4; ++k) col[row_ptr[d[k]] + pos[k]] = s[k];
}

__global__ void selffill_kernel(const int* __restrict__ row_ptr, const int* __restrict__ cnt,
                                int* __restrict__ col) {
    int i = blockIdx.x * blockDim.x + threadIdx.x;
    if (i >= NN) return;
    col[row_ptr[i] + cnt[i]] = i;  // self edge last in the row
}

// ax = Ahat @ x = dis_i * sum_j xs[j]   (CSR includes self loop)
__global__ void aggx_kernel(const float* __restrict__ xs, const int* __restrict__ row_ptr,
                            const int* __restrict__ col, const float* __restrict__ dis,
                            float* __restrict__ ax) {
    int i = blockIdx.x * blockDim.x + threadIdx.x;
    if (i >= NN) return;
    float a0 = 0.f, a1 = 0.f, a2 = 0.f;
    int e = row_ptr[i + 1];
    for (int p = row_ptr[i]; p < e; ++p) {
        int j = col[p];
        a0 += xs[j * 3 + 0];
        a1 += xs[j * 3 + 1];
        a2 += xs[j * 3 + 2];
    }
    float d = dis[i];
    ax[i * 3 + 0] = d * a0; ax[i * 3 + 1] = d * a1; ax[i * 3 + 2] = d * a2;
}

// t16 = fp16(dis * relu(ax @ Wp + bp));  xr = ax @ Wr[64:67,:] + br
__global__ void proj_kernel(const float* __restrict__ ax,
                            const float* __restrict__ Wp, const float* __restrict__ bp,
                            const float* __restrict__ Wr, const float* __restrict__ br,
                            const float* __restrict__ dis,
                            __half* __restrict__ t16, float* __restrict__ xr) {
    int g = blockIdx.x * blockDim.x + threadIdx.x;
    if (g >= NN * 64) return;
    int i = g >> 6, c = g & 63;
    float a0 = ax[i * 3 + 0], a1 = ax[i * 3 + 1], a2 = ax[i * 3 + 2];
    float tp = fmaxf(a0 * Wp[c] + a1 * Wp[64 + c] + a2 * Wp[128 + c] + bp[c], 0.f);
    t16[g] = __float2half(tp * dis[i]);
    xr[g] = a0 * Wr[64 * 64 + c] + a1 * Wr[65 * 64 + c] + a2 * Wr[66 * 64 + c] + br[c];
}

// ---------------- fused GCN ----------------
// h16 rows fp16, pre-scaled by dis[j]. agg_i = dis_i * sum_{j in row} h16[j].
// Phase 1: two rows per wave iteration (rr, rr+8): 4 colv loads + 4 uint4
// gathers (32 edges) in flight; masked-FMA tails; interleaved shfl reduces.
// Phase 2: [64 x IN_W] fp32 @ [IN_W x OUT_W], W from global (L1-resident).

__device__ __forceinline__ void acc8_fma(float* a, float m, uint4 r) {
    union { uint4 u; __half2 h[4]; } cv;
    cv.u = r;
#pragma unroll
    for (int t = 0; t < 4; ++t) {
        float2 f = __half22float2(cv.h[t]);
        a[2 * t]     = fmaf(m, f.x, a[2 * t]);
        a[2 * t + 1] = fmaf(m, f.y, a[2 * t + 1]);
    }
}

template <int IN_W, int OUT_W, bool RELU, bool HAS_ADD, bool HAS_BIAS, bool W32, bool W16>
__global__ __launch_bounds__(256, 5) void gcn_kernel(
    const __half* __restrict__ h16, const float* __restrict__ Wg,
    const float* __restrict__ bias, const float* __restrict__ addsrc,
    const int* __restrict__ row_ptr, const int* __restrict__ colv,
    const float* __restrict__ dis,
    float* __restrict__ out32, __half* __restrict__ out16) {
    constexpr int TILE_R = 64;
    constexpr int QUADS = IN_W / 8;      // lanes per row (16B = 8 halves each)
    constexpr int SLOTS = 64 / QUADS;    // rows gathered per wave instruction
    constexpr int STR = IN_W + 4;
    __shared__ __align__(16) float aggT[TILE_R][STR];

    const int tid = threadIdx.x;
    const int tile0 = blockIdx.x * TILE_R;
    const int wave = tid >> 6;
    const int lane = tid & 63;
    const int fq = lane & (QUADS - 1);
    const int slot = lane / QUADS;

    for (int pr = 0; pr < 8; ++pr) {
        const int rA = (wave << 4) + pr;
        const int rB = rA + 8;
        const int iA = tile0 + rA, iB = tile0 + rB;
        float dA = 0.f, dB = 0.f;
        int sA = 0, eA = 0, sB = 0, eB = 0;
        if (iA < NN) { dA = dis[iA]; sA = row_ptr[iA]; eA = row_ptr[iA + 1]; }
        if (iB < NN) { dB = dis[iB]; sB = row_ptr[iB]; eB = row_ptr[iB + 1]; }
        sA = __builtin_amdgcn_readfirstlane(sA);
        eA = __builtin_amdgcn_readfirstlane(eA);
        sB = __builtin_amdgcn_readfirstlane(sB);
        eB = __builtin_amdgcn_readfirstlane(eB);
        const int lastA = (eA > 0) ? eA - 1 : 0;
        const int lastB = (eB > 0) ? eB - 1 : 0;
        const int nb = max(eA - sA, eB - sB);

        float accA[8], accB[8];
#pragma unroll
        for (int t = 0; t < 8; ++t) { accA[t] = 0.f; accB[t] = 0.f; }

        for (int off = 0; off < nb; off += 2 * SLOTS) {
            const int pA0 = sA + off + slot, pA1 = pA0 + SLOTS;
            const int pB0 = sB + off + slot, pB1 = pB0 + SLOTS;
            const float mA0 = (pA0 < eA) ? 1.f : 0.f;
            const float mA1 = (pA1 < eA) ? 1.f : 0.f;
            const float mB0 = (pB0 < eB) ? 1.f : 0.f;
            const float mB1 = (pB1 < eB) ? 1.f : 0.f;
            const int jA0 = colv[min(pA0, lastA)];
            const int jA1 = colv[min(pA1, lastA)];
            const int jB0 = colv[min(pB0, lastB)];
            const int jB1 = colv[min(pB1, lastB)];
            const uint4 gA0 = *(const uint4*)(h16 + (size_t)jA0 * IN_W + (fq << 3));
            const uint4 gA1 = *(const uint4*)(h16 + (size_t)jA1 * IN_W + (fq << 3));
            const uint4 gB0 = *(const uint4*)(h16 + (size_t)jB0 * IN_W + (fq << 3));
            const uint4 gB1 = *(const uint4*)(h16 + (size_t)jB1 * IN_W + (fq << 3));
            acc8_fma(accA, mA0, gA0);
            acc8_fma(accA, mA1, gA1);
            acc8_fma(accB, mB0, gB0);
            acc8_fma(accB, mB1, gB1);
        }
#pragma unroll
        for (int m = QUADS; m < 64; m <<= 1) {
#pragma unroll
            for (int t = 0; t < 8; ++t) accA[t] += __shfl_xor(accA[t], m, 64);
#pragma unroll
            for (int t = 0; t < 8; ++t) accB[t] += __shfl_xor(accB[t], m, 64);
        }
        if (slot == 0) {
#pragma unroll
            for (int t = 0; t < 8; ++t) { accA[t] *= dA; accB[t] *= dB; }
            *(float4*)&aggT[rA][(fq << 3)]     = make_float4(accA[0], accA[1], accA[2], accA[3]);
            *(float4*)&aggT[rA][(fq << 3) + 4] = make_float4(accA[4], accA[5], accA[6], accA[7]);
            *(float4*)&aggT[rB][(fq << 3)]     = make_float4(accB[0], accB[1], accB[2], accB[3]);
            *(float4*)&aggT[rB][(fq << 3) + 4] = make_float4(accB[4], accB[5], accB[6], accB[7]);
        }
    }
    __syncthreads();

    // phase 2
    constexpr int CPT = (OUT_W >= 4) ? 4 : OUT_W;
    constexpr int TXN = OUT_W / CPT;
    const int tx = tid % TXN;
    const int ty = tid / TXN;
    if (ty < TILE_R / 4) {
        float c[4][CPT];
#pragma unroll
        for (int r = 0; r < 4; ++r)
#pragma unroll
            for (int q = 0; q < CPT; ++q) c[r][q] = 0.f;

#pragma unroll 2
        for (int k4 = 0; k4 < IN_W / 4; ++k4) {
            float4 av[4];
#pragma unroll
            for (int r = 0; r < 4; ++r) av[r] = *(const float4*)&aggT[ty * 4 + r][k4 << 2];
#pragma unroll
            for (int kk = 0; kk < 4; ++kk) {
                float wv[CPT];
                if constexpr (CPT == 4) {
                    const float4 w4 = *(const float4*)(Wg + ((k4 << 2) + kk) * OUT_W + (tx << 2));
                    wv[0] = w4.x; wv[1] = w4.y; wv[2] = w4.z; wv[3] = w4.w;
                } else {
#pragma unroll
                    for (int q = 0; q < CPT; ++q)
                        wv[q] = Wg[((k4 << 2) + kk) * OUT_W + tx * CPT + q];
                }
#pragma unroll
                for (int r = 0; r < 4; ++r) {
                    const float ar = ((const float*)&av[r])[kk];
#pragma unroll
                    for (int q = 0; q < CPT; ++q) c[r][q] += ar * wv[q];
                }
            }
        }
        float bq[CPT];
#pragma unroll
        for (int q = 0; q < CPT; ++q) bq[q] = HAS_BIAS ? bias[tx * CPT + q] : 0.f;
#pragma unroll
        for (int r = 0; r < 4; ++r) {
            const int i = tile0 + ty * 4 + r;
            if (i < NN) {
                float o[CPT];
#pragma unroll
                for (int q = 0; q < CPT; ++q) o[q] = c[r][q] + bq[q];
                if constexpr (HAS_ADD) {
#pragma unroll
                    for (int q = 0; q < CPT; ++q) o[q] += addsrc[i * OUT_W + tx * CPT + q];
                }
                if constexpr (RELU) {
#pragma unroll
                    for (int q = 0; q < CPT; ++q) o[q] = fmaxf(o[q], 0.f);
                }
                if constexpr (W32) {
                    if constexpr (CPT == 4) {
                        *(float4*)(out32 + i * OUT_W + (tx << 2)) =
                            make_float4(o[0], o[1], o[2], o[3]);
                    } else {
#pragma unroll
                        for (int q = 0; q < CPT; ++q) out32[i * OUT_W + tx * CPT + q] = o[q];
                    }
                }
                if constexpr (W16) {
                    const float d = dis[i];
                    if constexpr (CPT == 4) {
                        union { uint2 u; __half2 h[2]; } pk;
                        pk.h[0] = __float22half2_rn(make_float2(o[0] * d, o[1] * d));
                        pk.h[1] = __float22half2_rn(make_float2(o[2] * d, o[3] * d));
                        *(uint2*)(out16 + i * OUT_W + (tx << 2)) = pk.u;
                    } else {
#pragma unroll
                        for (int q = 0; q < CPT; ++q)
                            out16[i * OUT_W + tx * CPT + q] = __float2half(o[q] * d);
                    }
                }
            }
        }
    }
}

// ---------------- driver ----------------

extern "C" void kernel_launch(void* const* d_in, const int* in_sizes, int n_in,
                              void* d_out, int out_size, void* d_ws, size_t ws_size,
                              hipStream_t stream) {
    const float* x   = (const float*)d_in[0];
    const float* Wp  = (const float*)d_in[1];
    const float* bp  = (const float*)d_in[2];
    const float* Wr  = (const float*)d_in[3];
    const float* br  = (const float*)d_in[4];
    const float* W11 = (const float*)d_in[5];
    const float* b11 = (const float*)d_in[6];
    const float* W12 = (const float*)d_in[7];
    const float* b12 = (const float*)d_in[8];
    const float* W21 = (const float*)d_in[9];
    const float* b21 = (const float*)d_in[10];
    const float* W22 = (const float*)d_in[11];
    const float* b22 = (const float*)d_in[12];
    const float* Wh1 = (const float*)d_in[13];
    const float* bh1 = (const float*)d_in[14];
    const float* Wh2 = (const float*)d_in[15];
    const float* bh2 = (const float*)d_in[16];
    const float* Wh3 = (const float*)d_in[17];
    const float* bh3 = (const float*)d_in[18];
    const int* edge  = (const int*)d_in[19];
    const int* srcA = edge;
    const int* dstA = edge + NE;
    float* outp = (float*)d_out;

    char* p = (char*)d_ws;
    auto carve = [&](size_t bytes) {
        char* r = p;
        p += (bytes + 255) & ~(size_t)255;
        return r;
    };
    int*    cnt  = (int*)carve(NN * 4);
    int*    fil  = (int*)carve(NN * 4);
    int*    rptr = (int*)carve((NN + 1) * 4);
    float*  dis  = (float*)carve(NN * 4);
    int*    sums = (int*)carve(128 * 4);
    int*    colv = (int*)carve((size_t)(NE + NN + 256) * 4);
    float*  xs   = (float*)carve((size_t)NN * 3 * 4);
    float*  ax   = (float*)carve((size_t)NN * 3 * 4);
    float*  xr   = (float*)carve((size_t)NN * 64 * 4);
    float*  bu32 = (float*)carve((size_t)NN * 64 * 4);
    float*  bw32 = (float*)carve((size_t)NN * 64 * 4);
    __half* bt16 = (__half*)carve((size_t)NN * 64 * 2);
    __half* bu16 = (__half*)carve((size_t)NN * 64 * 2);
    __half* bv16 = (__half*)carve((size_t)NN * 64 * 2);
    __half* bw16 = (__half*)carve((size_t)NN * 64 * 2);

    hipMemsetAsync(cnt, 0, NN * 4, stream);
    hipMemsetAsync(fil, 0, NN * 4, stream);
    count_kernel<<<(NE / 4 + 255) / 256, 256, 0, stream>>>(dstA, cnt);
    dis_xs_kernel<<<(NN + 255) / 256, 256, 0, stream>>>(cnt, x, dis, xs);
    scan1_kernel<<<NCHUNK, 256, 0, stream>>>(cnt, rptr, sums);
    scan2_kernel<<<1, 128, 0, stream>>>(sums, rptr);
    scan3_kernel<<<(NN + 255) / 256, 256, 0, stream>>>(rptr, sums);
    fill_kernel<<<(NE / 4 + 255) / 256, 256, 0, stream>>>(srcA, dstA, rptr, fil, colv);
    selffill_kernel<<<(NN + 255) / 256, 256, 0, stream>>>(rptr, cnt, colv);
    aggx_kernel<<<(NN + 255) / 256, 256, 0, stream>>>(xs, rptr, colv, dis, ax);
    proj_kernel<<<(NN * 64 + 255) / 256, 256, 0, stream>>>(ax, Wp, bp, Wr, br, dis, bt16, xr);

    const int GB = (NN + 63) / 64;
    for (int it = 0; it < 5; ++it) {
        gcn_kernel<64, 64, false, true, false, true, true><<<GB, 256, 0, stream>>>(
            bt16, Wr, nullptr, xr, rptr, colv, dis, bu32, bu16);
        gcn_kernel<64, 64, true, false, true, false, true><<<GB, 256, 0, stream>>>(
            bu16, W11, b11, nullptr, rptr, colv, dis, nullptr, bv16);
        gcn_kernel<64, 64, true, true, true, true, true><<<GB, 256, 0, stream>>>(
            bv16, W12, b12, bu32, rptr, colv, dis, bw32, bw16);
        gcn_kernel<64, 64, true, false, true, false, true><<<GB, 256, 0, stream>>>(
            bw16, W21, b21, nullptr, rptr, colv, dis, nullptr, bv16);
        gcn_kernel<64, 64, true, true, true, false, true><<<GB, 256, 0, stream>>>(
            bv16, W22, b22, bw32, rptr, colv, dis, nullptr, bt16);
    }
    gcn_kernel<64, 32, true, false, true, false, true><<<GB, 256, 0, stream>>>(
        bt16, Wh1, bh1, nullptr, rptr, colv, dis, nullptr, bv16);
    gcn_kernel<32, 8, true, false, true, false, true><<<GB, 256, 0, stream>>>(
        bv16, Wh2, bh2, nullptr, rptr, colv, dis, nullptr, bw16);
    gcn_kernel<8, 2, false, false, true, true, false><<<GB, 256, 0, stream>>>(
        bw16, Wh3, bh3, nullptr, rptr, colv, dis, outp, nullptr);
}